// Round 1
// baseline (93.648 us; speedup 1.0000x reference)
//
#include <hip/hip_runtime.h>

#define MAX_NUM_ATOMS 13

// One block per output row n. Block computes out[n, 0:O] (O=512) as a
// vector-matrix product fact_prod[n,:] @ params[ids[n]] + bias[ids[n]].
// fact_prod staged in LDS (all-lane broadcast reads). Each thread owns 4
// consecutive output columns -> every h-step is one coalesced float4 load
// per lane across a contiguous W row (2KB / wave-pair).
__global__ void honet_rowgemv(const int* __restrict__ x,
                              const int* __restrict__ fact,
                              const float* __restrict__ inp,
                              const float* __restrict__ params,
                              const float* __restrict__ bias,
                              const int* __restrict__ msg_to_p,
                              const int* __restrict__ order_p,
                              float* __restrict__ out,
                              int N, int H, int O, int ORDER) {
    extern __shared__ float fp[];  // H floats

    const int n = blockIdx.x;
    if (n >= N) return;

    const int msg_to = *msg_to_p;
    const int order  = *order_p;
    (void)ORDER;

    // weight-matrix id for this row
    const int f0 = fact[2 * n];
    const int a1 = x[f0 * 3 + 1];
    const int a2 = x[f0 * 3 + 2];
    const int id = a1 * MAX_NUM_ATOMS + a2;

    // stage fact_prod[n, :] = prod_{i != msg_to} inp[i, n, :] into LDS
    for (int h = threadIdx.x; h < H; h += blockDim.x) {
        float p = 1.0f;
        for (int i = 0; i < order; ++i) {
            if (i != msg_to) {
                p *= inp[(size_t)i * N * H + (size_t)n * H + h];
            }
        }
        fp[h] = p;
    }
    __syncthreads();

    const float* __restrict__ W = params + (size_t)id * H * O;
    const int o0 = threadIdx.x * 4;

    float4 acc = make_float4(0.f, 0.f, 0.f, 0.f);
#pragma unroll 8
    for (int h = 0; h < H; ++h) {
        const float4 w = *(const float4*)(W + (size_t)h * O + o0);
        const float s = fp[h];
        acc.x += s * w.x;
        acc.y += s * w.y;
        acc.z += s * w.z;
        acc.w += s * w.w;
    }

    const float4 b = *(const float4*)(bias + (size_t)id * O + o0);
    acc.x += b.x;
    acc.y += b.y;
    acc.z += b.z;
    acc.w += b.w;

    *(float4*)(out + (size_t)n * O + o0) = acc;
}

extern "C" void kernel_launch(void* const* d_in, const int* in_sizes, int n_in,
                              void* d_out, int out_size, void* d_ws, size_t ws_size,
                              hipStream_t stream) {
    const int*   x      = (const int*)d_in[0];
    const int*   fact   = (const int*)d_in[1];
    const float* inp    = (const float*)d_in[2];
    const float* params = (const float*)d_in[3];
    const float* bias   = (const float*)d_in[4];
    const int*   msg_to = (const int*)d_in[5];
    const int*   order  = (const int*)d_in[6];
    float*       out    = (float*)d_out;

    const int NP = MAX_NUM_ATOMS * MAX_NUM_ATOMS;        // 169
    const int N  = in_sizes[1] / 2;                      // 1024
    const int O  = in_sizes[4] / NP;                     // 512
    const int H  = in_sizes[3] / (NP * O);               // 512
    const int ORDER = in_sizes[2] / (N * H);             // 3

    dim3 grid(N);
    dim3 block(O / 4);                                   // 128 threads
    size_t shmem = (size_t)H * sizeof(float);
    hipLaunchKernelGGL(honet_rowgemv, grid, block, shmem, stream,
                       x, fact, inp, params, bias, msg_to, order, out,
                       N, H, O, ORDER);
}